// Round 9
// baseline (138.327 us; speedup 1.0000x reference)
//
#include <hip/hip_runtime.h>
#include <math.h>

// GptOssRouter: T=16384, H=2880, E=128, K=4.
// K1: split-bf16 3-pass MFMA GEMM: v = h + l (h=trunc_bf16(v), l=trunc_bf16(v-h),
//     both exact) -> logit = xh*wh + xh*wl + xl*wh, err sigma ~7e-6.
//     LDS: row=256B (h|l), XOR-swizzle byte^=((row&7)<<4) -> conflict-free
//     ds_write_b64 / ds_read_b128. KC=64 floats, 45 chunks, double-buffered.
// K2: rank-based top-8 from logits; certified-gap test (TAU=2.5e-4 ~ 35 sigma):
//     fast path softmax straight from fp32 logits; rare slow path does fp64
//     re-accumulation of the 8 candidates (order == float64 numpy reference).

#define T_TOK 16384
#define HDIM  2880
#define EEXP  128
#define KTOP  4

// ---------------- Kernel 1 ----------------
#define TM    32            // tokens per block
#define EN    64            // experts per block
#define NT1   256           // 4 waves
#define KC    64            // K-chunk floats (2880 = 45*64)
#define NCH   (HDIM / KC)   // 45
#define LDROW 256           // bytes: 128 h + 128 l (swizzled within halves)
#define ROWS  (TM + EN)     // 96 rows
#define BUFB  (ROWS * LDROW)// 24576 per buffer
#define NPF   6             // float4 per thread per chunk (96*16/256)

typedef __attribute__((ext_vector_type(8))) short bf16x8;
typedef __attribute__((ext_vector_type(4))) float f32x4;

// split v into h = trunc_bf16(v) (exact), l = trunc_bf16(v - h) (exact);
// 8B h-words at row base + swizzled c4 slot, 8B l-words at +128.
static __device__ __forceinline__ void split_write(char* base, int row, int c4, float4 v) {
    union { float4 v4; unsigned u[4]; } uv; uv.v4 = v;
    unsigned h01 = __builtin_amdgcn_perm(uv.u[1], uv.u[0], 0x07060302u);
    unsigned h23 = __builtin_amdgcn_perm(uv.u[3], uv.u[2], 0x07060302u);
    float r0 = v.x - __uint_as_float(uv.u[0] & 0xffff0000u);
    float r1 = v.y - __uint_as_float(uv.u[1] & 0xffff0000u);
    float r2 = v.z - __uint_as_float(uv.u[2] & 0xffff0000u);
    float r3 = v.w - __uint_as_float(uv.u[3] & 0xffff0000u);
    unsigned l01 = __builtin_amdgcn_perm(__float_as_uint(r1), __float_as_uint(r0), 0x07060302u);
    unsigned l23 = __builtin_amdgcn_perm(__float_as_uint(r3), __float_as_uint(r2), 0x07060302u);
    int off = row * LDROW + ((c4 * 8) ^ ((row & 7) << 4));
    uint2 hw; hw.x = h01; hw.y = h23;
    uint2 lw; lw.x = l01; lw.y = l23;
    *(uint2*)(base + off)       = hw;
    *(uint2*)(base + off + 128) = lw;
}

__global__ __launch_bounds__(NT1, 3) void router_gemm(
    const float* __restrict__ x, const float* __restrict__ w,
    const float* __restrict__ bias, float* __restrict__ out)
{
    __shared__ char smem[2 * BUFB];     // 49152 B
    const int tid = threadIdx.x;
    const int blk = blockIdx.x;
    const int xcd = blk & 7;
    const int j   = blk >> 3;           // 0..127 within XCD
    const int be  = j & 1;              // expert half
    const int p   = xcd * 64 + (j >> 1);// token tile 0..511
    const int tok0 = p * TM;
    const int e0   = be * EN;

    const int lane = tid & 63;
    const int wv   = tid >> 6;
    const int wt   = wv & 1;            // token 16-row group
    const int wn   = wv >> 1;           // expert 32-col group
    const int r    = lane & 15;
    const int g    = lane >> 4;

    // staging map: 96 rows x 16 float4 = 1536 float4, 6 per thread
    const float* sptr[NPF];
    int srow[NPF], sc4[NPF];
#pragma unroll
    for (int i = 0; i < NPF; ++i) {
        int f = tid + i * NT1;
        int row = f >> 4, c4 = f & 15;
        srow[i] = row; sc4[i] = c4;
        sptr[i] = (row < TM) ? (x + (size_t)(tok0 + row) * HDIM + c4 * 4)
                             : (w + (size_t)(e0 + row - TM) * HDIM + c4 * 4);
    }

    // swizzled read offsets (per lane, fixed): a row and the two b rows
    const int arow = wt * 16 + r;
    const int brow0 = TM + wn * 32 + r;
    const int brow1 = TM + wn * 32 + 16 + r;
    int aoff[2], boff0[2], boff1[2];
#pragma unroll
    for (int ks = 0; ks < 2; ++ks) {
        aoff[ks]  = arow  * LDROW + ((ks * 64 + g * 16) ^ ((arow  & 7) << 4));
        boff0[ks] = brow0 * LDROW + ((ks * 64 + g * 16) ^ ((brow0 & 7) << 4));
        boff1[ks] = brow1 * LDROW + ((ks * 64 + g * 16) ^ ((brow1 & 7) << 4));
    }

    f32x4 acc[2];
    const f32x4 zf = {0.f, 0.f, 0.f, 0.f};
    acc[0] = zf; acc[1] = zf;

    float4 pf[NPF];
    // prologue: chunk 0 -> regs -> buf0
#pragma unroll
    for (int i = 0; i < NPF; ++i) pf[i] = *(const float4*)sptr[i];
#pragma unroll
    for (int i = 0; i < NPF; ++i) split_write(smem, srow[i], sc4[i], pf[i]);
    __syncthreads();

    for (int c = 0; c < NCH; ++c) {
        char* cb = smem + (c & 1) * BUFB;        // compute buffer
        char* sb = smem + ((c & 1) ^ 1) * BUFB;  // stage buffer
        const bool more = (c + 1 < NCH);
        if (more) {
            int koff = (c + 1) * KC;
#pragma unroll
            for (int i = 0; i < NPF; ++i)
                pf[i] = *(const float4*)(sptr[i] + koff);
        }
#pragma unroll
        for (int ks = 0; ks < 2; ++ks) {
            bf16x8 ah = *(const bf16x8*)(cb + aoff[ks]);
            bf16x8 al = *(const bf16x8*)(cb + aoff[ks] + 128);
            bf16x8 bh0 = *(const bf16x8*)(cb + boff0[ks]);
            bf16x8 bl0 = *(const bf16x8*)(cb + boff0[ks] + 128);
            bf16x8 bh1 = *(const bf16x8*)(cb + boff1[ks]);
            bf16x8 bl1 = *(const bf16x8*)(cb + boff1[ks] + 128);
            acc[0] = __builtin_amdgcn_mfma_f32_16x16x32_bf16(ah, bh0, acc[0], 0, 0, 0);
            acc[1] = __builtin_amdgcn_mfma_f32_16x16x32_bf16(ah, bh1, acc[1], 0, 0, 0);
            acc[0] = __builtin_amdgcn_mfma_f32_16x16x32_bf16(ah, bl0, acc[0], 0, 0, 0);
            acc[1] = __builtin_amdgcn_mfma_f32_16x16x32_bf16(ah, bl1, acc[1], 0, 0, 0);
            acc[0] = __builtin_amdgcn_mfma_f32_16x16x32_bf16(al, bh0, acc[0], 0, 0, 0);
            acc[1] = __builtin_amdgcn_mfma_f32_16x16x32_bf16(al, bh1, acc[1], 0, 0, 0);
        }
        if (more) {
#pragma unroll
            for (int i = 0; i < NPF; ++i) split_write(sb, srow[i], sc4[i], pf[i]);
        }
        __syncthreads();
    }

    // epilogue: logits(+bias) -> out score rows (scratch for K2)
#pragma unroll
    for (int n = 0; n < 2; ++n) {
        int e = e0 + wn * 32 + n * 16 + r;
        float bv = bias[e];
#pragma unroll
        for (int q = 0; q < 4; ++q) {
            int m = wt * 16 + g * 4 + q;
            out[(size_t)(tok0 + m) * EEXP + e] = acc[n][q] + bv;
        }
    }
}

// ---------------- Kernel 2 ----------------
#define NT2 256
#define TAU 2.5e-4f

__global__ __launch_bounds__(NT2) void router_select(
    const float* __restrict__ x, const float* __restrict__ w,
    const float* __restrict__ bias, float* __restrict__ out)
{
    __shared__ float  lrow[2][EEXP];
    __shared__ float  srow[2][EEXP];
    __shared__ float  cvf[2][8];
    __shared__ int    cie[2][8];
    __shared__ double cvd[2][8];
    __shared__ double sv4[2][4];
    __shared__ int    si4[2][4];
    __shared__ int    flg[2];

    const int tid = threadIdx.x;
    const int tg  = tid >> 7;           // token group 0/1
    const int e   = tid & 127;
    const int t   = blockIdx.x * 2 + tg;
    float* orow = out + (size_t)t * EEXP;

    float my = orow[e];                 // coalesced logit load
    lrow[tg][e] = my;
    srow[tg][e] = 0.f;
    __syncthreads();

    // parallel rank among 128 (strict total order, index tie-break)
    int rank = 0;
    const float4* lr4 = (const float4*)lrow[tg];
#pragma unroll 8
    for (int j4 = 0; j4 < EEXP / 4; ++j4) {
        float4 lv = lr4[j4];
        int jb = j4 * 4;
        rank += (lv.x > my) || (lv.x == my && (jb + 0) < e);
        rank += (lv.y > my) || (lv.y == my && (jb + 1) < e);
        rank += (lv.z > my) || (lv.z == my && (jb + 2) < e);
        rank += (lv.w > my) || (lv.w == my && (jb + 3) < e);
    }
    if (rank < 8) { cvf[tg][rank] = my; cie[tg][rank] = e; }
    __syncthreads();

    // certified-gap test on the 4 order-relevant gaps
    if (e == 0) {
        float gmin = 3.4e38f;
#pragma unroll
        for (int k = 0; k < 4; ++k)
            gmin = fminf(gmin, cvf[tg][k] - cvf[tg][k + 1]);
        flg[tg] = (gmin < TAU);
    }
    __syncthreads();
    const bool slow = (flg[tg] != 0);

    if (slow) {                          // rare: fp64 re-accumulation, 16 lanes/cand
        const int c = e >> 4, s = e & 15;
        const int ce = cie[tg][c];
        const float4* xr = (const float4*)(x + (size_t)t * HDIM);
        const float4* wr = (const float4*)(w + (size_t)ce * HDIM);
        double a0 = 0.0, a1 = 0.0, a2 = 0.0, a3 = 0.0;
        for (int i = 0; i < 45; ++i) {  // 45*16 = 720 float4
            int fi = s + i * 16;
            float4 xv = xr[fi];
            float4 wv = wr[fi];
            a0 = fma((double)xv.x, (double)wv.x, a0);
            a1 = fma((double)xv.y, (double)wv.y, a1);
            a2 = fma((double)xv.z, (double)wv.z, a2);
            a3 = fma((double)xv.w, (double)wv.w, a3);
        }
        double acc = (a0 + a2) + (a1 + a3);
#pragma unroll
        for (int off = 8; off > 0; off >>= 1)
            acc += __shfl_xor(acc, off); // closes within each 16-lane group
        if (s == 0) cvd[tg][c] = acc + (double)bias[ce];
    }
    __syncthreads();
    if (slow && e < 8) {                 // fp64 rank among the 8 candidates
        double mv = cvd[tg][e]; int mi = cie[tg][e];
        int rk = 0;
#pragma unroll
        for (int j2 = 0; j2 < 8; ++j2) {
            double oj = cvd[tg][j2];
            rk += (oj > mv) || (oj == mv && cie[tg][j2] < mi);
        }
        if (rk < 4) { sv4[tg][rk] = mv; si4[tg][rk] = mi; }
    }
    __syncthreads();

    if (e < 4) {
        float sc; int id;
        if (slow) {
            double m = sv4[tg][0];
            double s0 = exp(sv4[tg][0] - m), s1 = exp(sv4[tg][1] - m);
            double s2 = exp(sv4[tg][2] - m), s3 = exp(sv4[tg][3] - m);
            double ssum = ((s0 + s1) + (s2 + s3));
            double ek = exp(sv4[tg][e] - m);
            sc = (float)(ek / ssum); id = si4[tg][e];
        } else {
            float m = cvf[tg][0];
            float s0 = expf(cvf[tg][0] - m), s1 = expf(cvf[tg][1] - m);
            float s2 = expf(cvf[tg][2] - m), s3 = expf(cvf[tg][3] - m);
            float ssum = ((s0 + s1) + (s2 + s3));
            sc = expf(cvf[tg][e] - m) / ssum; id = cie[tg][e];
        }
        out[(size_t)T_TOK * EEXP + (size_t)t * KTOP + e] = (float)id;
        srow[tg][id] = sc;
    }
    __syncthreads();

    if (e < 32) ((float4*)orow)[e] = ((float4*)srow[tg])[e];
}

extern "C" void kernel_launch(void* const* d_in, const int* in_sizes, int n_in,
                              void* d_out, int out_size, void* d_ws, size_t ws_size,
                              hipStream_t stream) {
    const float* x    = (const float*)d_in[0];
    const float* w    = (const float*)d_in[1];
    const float* bias = (const float*)d_in[2];
    float* out        = (float*)d_out;

    hipLaunchKernelGGL(router_gemm, dim3((T_TOK / TM) * (EEXP / EN)), dim3(NT1),
                       0, stream, x, w, bias, out);
    hipLaunchKernelGGL(router_select, dim3(T_TOK / 2), dim3(NT2), 0, stream,
                       x, w, bias, out);
}

// Round 10
// 97.095 us; speedup vs baseline: 1.4247x; 1.4247x over previous
//
#include <hip/hip_runtime.h>
#include <math.h>

// GptOssRouter: T=16384, H=2880, E=128, K=4. Single fused kernel.
// Per block (grid=256, 512 thr): 64 tokens x all 128 experts.
// GEMM: split-bf16 3-pass MFMA (v = h + l, both trunc-bf16 exact splits;
//   logit = xh*wh + xh*wl + xl*wh, err sigma ~8e-6), KC=32, 90 chunks,
//   double-buffered LDS with depth-2 register prefetch.
// LDS layout: row = 128 B; h slot = (g ^ (row&7))*16, l at ^64 ->
//   bank-uniform (writes 4/bank, b128 reads 8/bank = HW minimum).
// Selection fused: stripe top-8 (8 thr/token) + shfl merge -> sorted top-8;
//   certified-gap test (TAU >> 30 sigma): fast path = fp32 softmax;
//   rare slow path: fp64 re-accumulation of 8 candidates (1 wave/candidate)
//   so top-4 ORDER matches the float64 numpy reference exactly.

#define T_TOK 16384
#define HDIM  2880
#define EEXP  128
#define KTOP  4

#define TM    64
#define NT    512
#define KC    32
#define NCH   (HDIM / KC)        // 90
#define ROWS  (TM + EEXP)        // 192
#define RB    128                // bytes per row (h 64 | l 64, interleaved by XOR)
#define BUFB  (ROWS * RB)        // 24576
#define TAU   2.5e-4f

typedef __attribute__((ext_vector_type(8))) short bf16x8;
typedef __attribute__((ext_vector_type(4))) float f32x4;

// v = h + l; h = trunc_bf16(v) (exact), l = trunc_bf16(v-h) (exact).
// 8B h-words at phys slot ((c4>>1)^(row&7)), 8B l-words at ^64.
static __device__ __forceinline__ void split_write(char* base, int off, float4 v) {
    union { float4 v4; unsigned u[4]; } uv; uv.v4 = v;
    unsigned h01 = __builtin_amdgcn_perm(uv.u[1], uv.u[0], 0x07060302u);
    unsigned h23 = __builtin_amdgcn_perm(uv.u[3], uv.u[2], 0x07060302u);
    float r0 = v.x - __uint_as_float(uv.u[0] & 0xffff0000u);
    float r1 = v.y - __uint_as_float(uv.u[1] & 0xffff0000u);
    float r2 = v.z - __uint_as_float(uv.u[2] & 0xffff0000u);
    float r3 = v.w - __uint_as_float(uv.u[3] & 0xffff0000u);
    unsigned l01 = __builtin_amdgcn_perm(__float_as_uint(r1), __float_as_uint(r0), 0x07060302u);
    unsigned l23 = __builtin_amdgcn_perm(__float_as_uint(r3), __float_as_uint(r2), 0x07060302u);
    uint2 hw; hw.x = h01; hw.y = h23;
    uint2 lw; lw.x = l01; lw.y = l23;
    *(uint2*)(base + off)        = hw;
    *(uint2*)(base + (off ^ 64)) = lw;
}

#define MFMA_OP __builtin_amdgcn_mfma_f32_16x16x32_bf16

__global__ __launch_bounds__(NT, 2) void router_fused(
    const float* __restrict__ x, const float* __restrict__ w,
    const float* __restrict__ bias, float* __restrict__ out)
{
    __shared__ char smem[2 * BUFB];     // 49152 B
    const int tid  = threadIdx.x;
    const int tok0 = blockIdx.x * TM;
    const int lane = tid & 63;
    const int wv   = tid >> 6;          // 0..7
    const int wt   = wv & 1;            // token 32-half
    const int wn   = wv >> 1;           // expert 32-group (0..3)
    const int r    = lane & 15;
    const int g    = lane >> 4;

    // staging map: 192 rows x 8 float4 = 1536 float4, 3 per thread
    const float* sptr[3];
    int soff[3];
#pragma unroll
    for (int i = 0; i < 3; ++i) {
        int f = tid + i * NT;
        int row = f >> 3, c4 = f & 7;
        soff[i] = row * RB + ((((c4 >> 1) ^ (row & 7)) << 4) | ((c4 & 1) << 3));
        sptr[i] = (row < TM) ? (x + (size_t)(tok0 + row) * HDIM + c4 * 4)
                             : (w + (size_t)(row - TM) * HDIM + c4 * 4);
    }

    // MFMA read offsets (all 16-aligned, bank-uniform)
    const int ar0 = wt * 32 + r,      ar1 = wt * 32 + 16 + r;
    const int br0 = TM + wn * 32 + r, br1 = TM + wn * 32 + 16 + r;
    const int aH0 = ar0 * RB + ((g ^ (ar0 & 7)) << 4);
    const int aH1 = ar1 * RB + ((g ^ (ar1 & 7)) << 4);
    const int bH0 = br0 * RB + ((g ^ (br0 & 7)) << 4);
    const int bH1 = br1 * RB + ((g ^ (br1 & 7)) << 4);

    f32x4 a00 = {0.f,0.f,0.f,0.f}, a01 = a00, a10 = a00, a11 = a00;

#define DO_MFMA(cb) do {                                            \
        bf16x8 ah0 = *(const bf16x8*)((cb) + aH0);                  \
        bf16x8 al0 = *(const bf16x8*)((cb) + (aH0 ^ 64));           \
        bf16x8 ah1 = *(const bf16x8*)((cb) + aH1);                  \
        bf16x8 al1 = *(const bf16x8*)((cb) + (aH1 ^ 64));           \
        bf16x8 bh0 = *(const bf16x8*)((cb) + bH0);                  \
        bf16x8 bl0 = *(const bf16x8*)((cb) + (bH0 ^ 64));           \
        bf16x8 bh1 = *(const bf16x8*)((cb) + bH1);                  \
        bf16x8 bl1 = *(const bf16x8*)((cb) + (bH1 ^ 64));           \
        a00 = MFMA_OP(ah0, bh0, a00, 0, 0, 0);                      \
        a01 = MFMA_OP(ah0, bh1, a01, 0, 0, 0);                      \
        a10 = MFMA_OP(ah1, bh0, a10, 0, 0, 0);                      \
        a11 = MFMA_OP(ah1, bh1, a11, 0, 0, 0);                      \
        a00 = MFMA_OP(ah0, bl0, a00, 0, 0, 0);                      \
        a01 = MFMA_OP(ah0, bl1, a01, 0, 0, 0);                      \
        a10 = MFMA_OP(ah1, bl0, a10, 0, 0, 0);                      \
        a11 = MFMA_OP(ah1, bl1, a11, 0, 0, 0);                      \
        a00 = MFMA_OP(al0, bh0, a00, 0, 0, 0);                      \
        a01 = MFMA_OP(al0, bh1, a01, 0, 0, 0);                      \
        a10 = MFMA_OP(al1, bh0, a10, 0, 0, 0);                      \
        a11 = MFMA_OP(al1, bh1, a11, 0, 0, 0);                      \
    } while (0)

#define LOADS(pf, ch) do { int k0_ = (ch) * KC;                     \
        pf[0] = *(const float4*)(sptr[0] + k0_);                    \
        pf[1] = *(const float4*)(sptr[1] + k0_);                    \
        pf[2] = *(const float4*)(sptr[2] + k0_); } while (0)

#define WRITES(pf, bb) do {                                         \
        split_write((bb), soff[0], pf[0]);                          \
        split_write((bb), soff[1], pf[1]);                          \
        split_write((bb), soff[2], pf[2]); } while (0)

    char* b0 = smem;
    char* b1 = smem + BUFB;
    float4 pfA[3], pfB[3];

    LOADS(pfA, 0);
    LOADS(pfB, 1);
    WRITES(pfA, b0);
    __syncthreads();

    for (int c = 0; c < NCH; c += 2) {
        if (c + 2 < NCH) LOADS(pfA, c + 2);   // depth-2 prefetch
        DO_MFMA(b0);
        WRITES(pfB, b1);                      // chunk c+1
        __syncthreads();
        if (c + 3 < NCH) LOADS(pfB, c + 3);
        DO_MFMA(b1);
        if (c + 2 < NCH) WRITES(pfA, b0);
        __syncthreads();
    }

    // ---------------- epilogue: logits(+bias) -> LDS [64][130] ---------------
    float* logitsL = (float*)smem;
    const float bv0 = bias[wn * 32 + r];
    const float bv1 = bias[wn * 32 + 16 + r];
#pragma unroll
    for (int q = 0; q < 4; ++q) {
        int m0 = wt * 32 + g * 4 + q, m1 = m0 + 16;
        int e0 = wn * 32 + r,         e1 = e0 + 16;
        logitsL[m0 * 130 + e0] = a00[q] + bv0;
        logitsL[m0 * 130 + e1] = a01[q] + bv1;
        logitsL[m1 * 130 + e0] = a10[q] + bv0;
        logitsL[m1 * 130 + e1] = a11[q] + bv1;
    }

    // overlay region (disjoint from logits [0,33280) and later srow [0,32768))
    float*  cvf = (float*) (smem + 33280);   // [64][8]
    int*    cie = (int*)   (smem + 35328);   // [64][8]
    int*    flg = (int*)   (smem + 37376);   // [64]
    double* svd = (double*)(smem + 37632);   // [64][4]
    int*    sid = (int*)   (smem + 39680);   // [64][4]
    double* cvd = (double*)(smem + 40704);   // [8]
    __syncthreads();

    // -------- stripe top-8: thread (t, s) scans experts [s*16, s*16+16) ------
    {
        const int t = tid >> 3, s = tid & 7;
        float v[8]; int id[8];
#pragma unroll
        for (int k = 0; k < 8; ++k) { v[k] = -3.4e38f; id[k] = 0x7fffffff; }
        for (int jj = 0; jj < 16; ++jj) {
            float lv = logitsL[t * 130 + s * 16 + jj];
            int   e  = s * 16 + jj;
            bool gt[8];
#pragma unroll
            for (int k = 0; k < 8; ++k)
                gt[k] = (lv > v[k]) || (lv == v[k] && e < id[k]);
#pragma unroll
            for (int k = 7; k >= 1; --k)
                if (gt[k - 1]) { v[k] = v[k - 1]; id[k] = id[k - 1]; }
#pragma unroll
            for (int k = 0; k < 8; ++k) {
                bool put = gt[k] && (k == 0 || !gt[k - 1]);
                if (put) { v[k] = lv; id[k] = e; }
            }
        }
        // merge 8 stripe-lists (width-8 shfl k-way merge, 8 rounds -> sorted)
#pragma unroll
        for (int rd = 0; rd < 8; ++rd) {
            float hv = v[0]; int hi = id[0];
#pragma unroll
            for (int off = 1; off < 8; off <<= 1) {
                float ov = __shfl_xor(hv, off);
                int   oi = __shfl_xor(hi, off);
                if (ov > hv || (ov == hv && oi < hi)) { hv = ov; hi = oi; }
            }
            if (s == 0) { cvf[t * 8 + rd] = hv; cie[t * 8 + rd] = hi; }
            bool mine = (v[0] == hv) && (id[0] == hi);
            if (mine) {
#pragma unroll
                for (int k = 0; k < 7; ++k) { v[k] = v[k + 1]; id[k] = id[k + 1]; }
                v[7] = -3.4e38f; id[7] = 0x7fffffff;
            }
        }
    }
    __syncthreads();

    // -------- certified-gap test + fast-path fill ---------------------------
    if (tid < TM) {
        float gmin = 3.4e38f;
#pragma unroll
        for (int k = 0; k < 4; ++k)
            gmin = fminf(gmin, cvf[tid * 8 + k] - cvf[tid * 8 + k + 1]);
        flg[tid] = (gmin < TAU);
    }
    if (tid < 256) {
        int t2 = tid >> 2, k = tid & 3;
        svd[t2 * 4 + k] = (double)cvf[t2 * 8 + k];
        sid[t2 * 4 + k] = cie[t2 * 8 + k];
    }
    __syncthreads();

    // -------- rare slow path: fp64 rescore (1 wave per candidate) -----------
    for (int ts = 0; ts < TM; ++ts) {
        if (!flg[ts]) continue;              // uniform across block
        const int ce = cie[ts * 8 + wv];
        const float4* xr = (const float4*)(x + (size_t)(tok0 + ts) * HDIM);
        const float4* wr = (const float4*)(w + (size_t)ce * HDIM);
        double q0 = 0.0, q1 = 0.0, q2 = 0.0, q3 = 0.0;
        for (int i2 = 0; i2 < 12; ++i2) {
            int fi = lane + i2 * 64;
            if (fi < HDIM / 4) {
                float4 xv = xr[fi];
                float4 wv4 = wr[fi];
                q0 = fma((double)xv.x, (double)wv4.x, q0);
                q1 = fma((double)xv.y, (double)wv4.y, q1);
                q2 = fma((double)xv.z, (double)wv4.z, q2);
                q3 = fma((double)xv.w, (double)wv4.w, q3);
            }
        }
        double accd = (q0 + q2) + (q1 + q3);
#pragma unroll
        for (int off = 32; off > 0; off >>= 1)
            accd += __shfl_xor(accd, off);
        if (lane == 0) cvd[wv] = accd + (double)bias[ce];
        __syncthreads();
        if (tid < 8) {                        // fp64 rank among 8 candidates
            double mv = cvd[tid]; int mi2 = cie[ts * 8 + tid];
            int rk = 0;
#pragma unroll
            for (int j2 = 0; j2 < 8; ++j2) {
                double oj = cvd[j2];
                rk += (oj > mv) || (oj == mv && cie[ts * 8 + j2] < mi2);
            }
            if (rk < 4) { svd[ts * 4 + rk] = mv; sid[ts * 4 + rk] = mi2; }
        }
        __syncthreads();
    }

    // -------- softmax + outputs ---------------------------------------------
    float* srow = (float*)smem;              // [64][128], overlays dead logits
    {
        float4 z4 = make_float4(0.f, 0.f, 0.f, 0.f);
#pragma unroll
        for (int i = 0; i < 4; ++i)
            ((float4*)srow)[tid + i * NT] = z4;
    }
    __syncthreads();

    if (tid < TM) {
        double m  = svd[tid * 4];
        double e0 = exp(svd[tid * 4 + 0] - m), e1 = exp(svd[tid * 4 + 1] - m);
        double e2 = exp(svd[tid * 4 + 2] - m), e3 = exp(svd[tid * 4 + 3] - m);
        double inv = 1.0 / ((e0 + e1) + (e2 + e3));
        float* oidx = out + (size_t)T_TOK * EEXP + (size_t)(tok0 + tid) * KTOP;
        int i0 = sid[tid * 4 + 0], i1 = sid[tid * 4 + 1];
        int i2 = sid[tid * 4 + 2], i3 = sid[tid * 4 + 3];
        oidx[0] = (float)i0; oidx[1] = (float)i1;
        oidx[2] = (float)i2; oidx[3] = (float)i3;
        srow[tid * EEXP + i0] = (float)(e0 * inv);
        srow[tid * EEXP + i1] = (float)(e1 * inv);
        srow[tid * EEXP + i2] = (float)(e2 * inv);
        srow[tid * EEXP + i3] = (float)(e3 * inv);
    }
    __syncthreads();

    float4* orow = (float4*)(out + (size_t)tok0 * EEXP);
#pragma unroll
    for (int i = 0; i < 4; ++i)
        orow[tid + i * NT] = ((float4*)srow)[tid + i * NT];
}

extern "C" void kernel_launch(void* const* d_in, const int* in_sizes, int n_in,
                              void* d_out, int out_size, void* d_ws, size_t ws_size,
                              hipStream_t stream) {
    const float* x    = (const float*)d_in[0];
    const float* w    = (const float*)d_in[1];
    const float* bias = (const float*)d_in[2];
    float* out        = (float*)d_out;

    hipLaunchKernelGGL(router_fused, dim3(T_TOK / TM), dim3(NT), 0, stream,
                       x, w, bias, out);
}

// Round 11
// 85.092 us; speedup vs baseline: 1.6256x; 1.1411x over previous
//
#include <hip/hip_runtime.h>
#include <math.h>

// GptOssRouter: T=16384, H=2880, E=128, K=4.
// K0: pre-split w (fp32 -> bf16 h/l, both trunc-exact) into d_ws, tiled
//     exactly as MFMA B-fragments: tile(F,c,ks,p)[lane] = 16B = 8 bf16 of
//     w[F*16 + (lane&15)][c*64 + ks*32 + (lane>>4)*8 ...+7].
// K1 (fused): per block 32 tokens x all 128 experts, grid=512 (2 blocks/CU).
//     x split h/l into swizzled LDS (2x8KB double buffer); w B-frags loaded
//     DIRECTLY global->VGPR from d_ws (no LDS staging), double-buffered regs,
//     prefetch 1 chunk ahead. 3-pass MFMA: xh*wh + xh*wl + xl*wh (err ~1e-5).
//     Fused stripe-top8 + certified-gap test (TAU=2.5e-4): fast fp32 softmax;
//     rare fp64 re-accumulation slow path (order == float64 numpy reference).

#define T_TOK 16384
#define HDIM  2880
#define EEXP  128
#define KTOP  4

#define TM   32
#define NT   256
#define KC   64
#define NCH  (HDIM / KC)     // 45
#define XBUF 8192            // 32 rows * 256 B
#define TAU  2.5e-4f

typedef __attribute__((ext_vector_type(8))) short bf16x8;
typedef __attribute__((ext_vector_type(4))) float f32x4;

#define MFMA(a, b, c) __builtin_amdgcn_mfma_f32_16x16x32_bf16((a), (b), (c), 0, 0, 0)

// ---------------- K0: w pre-split into fragment-tiled bf16 h/l -------------
__global__ __launch_bounds__(256) void w_split(
    const float* __restrict__ w, char* __restrict__ wp)
{
    const int gid  = blockIdx.x * 256 + threadIdx.x;   // 46080 total
    const int lane = gid & 63;
    const int q    = gid >> 6;        // 0..719
    const int ks   = q & 1;
    const int q2   = q >> 1;          // 0..359
    const int c    = q2 % NCH;
    const int F    = q2 / NCH;        // 0..7
    const int e    = F * 16 + (lane & 15);
    const int k0   = c * 64 + ks * 32 + (lane >> 4) * 8;

    const float* src = w + (size_t)e * HDIM + k0;
    float4 v0 = *(const float4*)(src);
    float4 v1 = *(const float4*)(src + 4);
    float vv[8] = {v0.x, v0.y, v0.z, v0.w, v1.x, v1.y, v1.z, v1.w};
    union { unsigned short s[8]; uint4 u; } H, L;
#pragma unroll
    for (int j = 0; j < 8; ++j) {
        unsigned u = __float_as_uint(vv[j]);
        H.s[j] = (unsigned short)(u >> 16);
        float rr = vv[j] - __uint_as_float(u & 0xffff0000u);
        L.s[j] = (unsigned short)(__float_as_uint(rr) >> 16);
    }
    const int tile = ((F * NCH + c) * 2 + ks) * 2;     // p=0 (h); l at +1
    *(uint4*)(wp + (size_t)tile * 1024 + lane * 16)       = H.u;
    *(uint4*)(wp + (size_t)(tile + 1) * 1024 + lane * 16) = L.u;
}

// x split: v = h + l (h = trunc_bf16(v), l = trunc_bf16(v - h), both exact);
// h 8B at swizzled slot, l at +128 within the 256B row.
static __device__ __forceinline__ void split_write256(char* base, int off, float4 v) {
    union { float4 v4; unsigned u[4]; } uv; uv.v4 = v;
    unsigned h01 = __builtin_amdgcn_perm(uv.u[1], uv.u[0], 0x07060302u);
    unsigned h23 = __builtin_amdgcn_perm(uv.u[3], uv.u[2], 0x07060302u);
    float r0 = v.x - __uint_as_float(uv.u[0] & 0xffff0000u);
    float r1 = v.y - __uint_as_float(uv.u[1] & 0xffff0000u);
    float r2 = v.z - __uint_as_float(uv.u[2] & 0xffff0000u);
    float r3 = v.w - __uint_as_float(uv.u[3] & 0xffff0000u);
    unsigned l01 = __builtin_amdgcn_perm(__float_as_uint(r1), __float_as_uint(r0), 0x07060302u);
    unsigned l23 = __builtin_amdgcn_perm(__float_as_uint(r3), __float_as_uint(r2), 0x07060302u);
    uint2 hw; hw.x = h01; hw.y = h23;
    uint2 lw; lw.x = l01; lw.y = l23;
    *(uint2*)(base + off)       = hw;
    *(uint2*)(base + off + 128) = lw;
}

// ---------------- K1: fused GEMM + selection --------------------------------
__global__ __launch_bounds__(NT, 2) void router_fused(
    const float* __restrict__ x, const char* __restrict__ wp,
    const float* __restrict__ w, const float* __restrict__ bias,
    float* __restrict__ out)
{
    __shared__ char smem[20480];
    const int tid  = threadIdx.x;
    const int tok0 = blockIdx.x * TM;
    const int lane = tid & 63;
    const int wv   = tid >> 6;          // expert 32-group 0..3
    const int r    = lane & 15;
    const int g    = lane >> 4;

    char* xb0 = smem;
    char* xb1 = smem + XBUF;

    // x staging map: 512 float4 / 256 thr = 2 per thread
    int xoff[2];
    const float* xptr[2];
#pragma unroll
    for (int i = 0; i < 2; ++i) {
        int f = tid + i * NT;
        int row = f >> 4, c4 = f & 15;
        xoff[i] = row * 256 + ((((c4 >> 1) ^ (row & 7)) << 4) | ((c4 & 1) << 3));
        xptr[i] = x + (size_t)(tok0 + row) * HDIM + c4 * 4;
    }

    // a-frag read offsets: [tokfrag][ks]
    int aoff[2][2];
#pragma unroll
    for (int tf = 0; tf < 2; ++tf) {
        int row = tf * 16 + r;
#pragma unroll
        for (int ks = 0; ks < 2; ++ks)
            aoff[tf][ks] = row * 256 + (((ks * 4 + g) ^ (row & 7)) << 4);
    }

    f32x4 a00 = {0.f, 0.f, 0.f, 0.f}, a01 = a00, a10 = a00, a11 = a00;

#define LOADX(pf, cc) do {                                            \
        pf[0] = *(const float4*)(xptr[0] + (cc) * KC);                \
        pf[1] = *(const float4*)(xptr[1] + (cc) * KC); } while (0)

#define WRITEX(pf, bb) do {                                           \
        split_write256((bb), xoff[0], pf[0]);                         \
        split_write256((bb), xoff[1], pf[1]); } while (0)

    // w frag tiles: idx = F2*4 + ks*2 + p
#define LOADW(W, cc) do {                                             \
        _Pragma("unroll")                                             \
        for (int F2 = 0; F2 < 2; ++F2)                                \
        _Pragma("unroll")                                             \
        for (int ks_ = 0; ks_ < 2; ++ks_)                             \
        _Pragma("unroll")                                             \
        for (int p_ = 0; p_ < 2; ++p_)                                \
            W[F2*4 + ks_*2 + p_] = *(const bf16x8*)(wp +              \
                (size_t)((((wv*2 + F2) * NCH + (cc)) * 2 + ks_) * 2 + p_) * 1024 \
                + lane * 16); } while (0)

#define MFMA_CHUNK(cb, W) do {                                        \
        _Pragma("unroll")                                             \
        for (int ks_ = 0; ks_ < 2; ++ks_) {                           \
            bf16x8 ah0 = *(const bf16x8*)((cb) + aoff[0][ks_]);       \
            bf16x8 al0 = *(const bf16x8*)((cb) + aoff[0][ks_] + 128); \
            bf16x8 ah1 = *(const bf16x8*)((cb) + aoff[1][ks_]);       \
            bf16x8 al1 = *(const bf16x8*)((cb) + aoff[1][ks_] + 128); \
            bf16x8 bh0 = W[ks_*2],     bl0 = W[ks_*2 + 1];            \
            bf16x8 bh1 = W[4 + ks_*2], bl1 = W[4 + ks_*2 + 1];        \
            a00 = MFMA(ah0, bh0, a00); a01 = MFMA(ah0, bh1, a01);     \
            a10 = MFMA(ah1, bh0, a10); a11 = MFMA(ah1, bh1, a11);     \
            a00 = MFMA(ah0, bl0, a00); a01 = MFMA(ah0, bl1, a01);     \
            a10 = MFMA(ah1, bl0, a10); a11 = MFMA(ah1, bl1, a11);     \
            a00 = MFMA(al0, bh0, a00); a01 = MFMA(al0, bh1, a01);     \
            a10 = MFMA(al1, bh0, a10); a11 = MFMA(al1, bh1, a11);     \
        } } while (0)

    float4 pf[2];
    bf16x8 wA[8], wB[8];

    LOADX(pf, 0);
    LOADW(wA, 0);
    WRITEX(pf, xb0);
    __syncthreads();

    for (int c = 0; c < NCH - 1; c += 2) {
        LOADX(pf, c + 1); LOADW(wB, c + 1);
        MFMA_CHUNK(xb0, wA);
        WRITEX(pf, xb1);
        __syncthreads();
        if (c + 2 < NCH) { LOADX(pf, c + 2); LOADW(wA, c + 2); }
        MFMA_CHUNK(xb1, wB);
        if (c + 2 < NCH) WRITEX(pf, xb0);
        __syncthreads();
    }
    MFMA_CHUNK(xb0, wA);                 // chunk 44
    __syncthreads();

    // -------- logits(+bias) -> LDS [32][130] --------------------------------
    float* logitsL = (float*)smem;
    const float bv0 = bias[wv * 32 + r];
    const float bv1 = bias[wv * 32 + 16 + r];
#pragma unroll
    for (int q = 0; q < 4; ++q) {
        int m0 = g * 4 + q, m1 = m0 + 16;
        int e0 = wv * 32 + r, e1 = e0 + 16;
        logitsL[m0 * 130 + e0] = a00[q] + bv0;
        logitsL[m0 * 130 + e1] = a01[q] + bv1;
        logitsL[m1 * 130 + e0] = a10[q] + bv0;
        logitsL[m1 * 130 + e1] = a11[q] + bv1;
    }
    float*  cvf = (float*) (smem + 16640);   // [32][8]
    int*    cie = (int*)   (smem + 17664);   // [32][8]
    int*    flg = (int*)   (smem + 18688);   // [32]
    double* svd = (double*)(smem + 18816);   // [32][4]
    int*    sid = (int*)   (smem + 19840);   // [32][4]
    double* cvd = (double*)(smem + 20352);   // [8]
    __syncthreads();

    // -------- stripe top-8: thread (t, s) scans experts [s*16, s*16+16) -----
    {
        const int t = tid >> 3, s = tid & 7;
        float v[8]; int id[8];
#pragma unroll
        for (int k = 0; k < 8; ++k) { v[k] = -3.4e38f; id[k] = 0x7fffffff; }
        for (int jj = 0; jj < 16; ++jj) {
            float lv = logitsL[t * 130 + s * 16 + jj];
            int   e  = s * 16 + jj;
            bool gt[8];
#pragma unroll
            for (int k = 0; k < 8; ++k)
                gt[k] = (lv > v[k]) || (lv == v[k] && e < id[k]);
#pragma unroll
            for (int k = 7; k >= 1; --k)
                if (gt[k - 1]) { v[k] = v[k - 1]; id[k] = id[k - 1]; }
#pragma unroll
            for (int k = 0; k < 8; ++k) {
                bool put = gt[k] && (k == 0 || !gt[k - 1]);
                if (put) { v[k] = lv; id[k] = e; }
            }
        }
#pragma unroll
        for (int rd = 0; rd < 8; ++rd) {
            float hv = v[0]; int hi = id[0];
#pragma unroll
            for (int off = 1; off < 8; off <<= 1) {
                float ov = __shfl_xor(hv, off);
                int   oi = __shfl_xor(hi, off);
                if (ov > hv || (ov == hv && oi < hi)) { hv = ov; hi = oi; }
            }
            if (s == 0) { cvf[t * 8 + rd] = hv; cie[t * 8 + rd] = hi; }
            bool mine = (v[0] == hv) && (id[0] == hi);
            if (mine) {
#pragma unroll
                for (int k = 0; k < 7; ++k) { v[k] = v[k + 1]; id[k] = id[k + 1]; }
                v[7] = -3.4e38f; id[7] = 0x7fffffff;
            }
        }
    }
    __syncthreads();

    // -------- certified-gap test + fast-path fill ---------------------------
    if (tid < TM) {
        float gmin = 3.4e38f;
#pragma unroll
        for (int k = 0; k < 4; ++k)
            gmin = fminf(gmin, cvf[tid * 8 + k] - cvf[tid * 8 + k + 1]);
        flg[tid] = (gmin < TAU);
    }
    if (tid < 128) {
        int t2 = tid >> 2, k = tid & 3;
        svd[t2 * 4 + k] = (double)cvf[t2 * 8 + k];
        sid[t2 * 4 + k] = cie[t2 * 8 + k];
    }
    __syncthreads();

    // -------- rare slow path: fp64 rescore (2 candidates per wave) ----------
    for (int ts = 0; ts < TM; ++ts) {
        if (!flg[ts]) continue;              // uniform across block
#pragma unroll
        for (int h2 = 0; h2 < 2; ++h2) {
            const int cand = wv * 2 + h2;
            const int ce = cie[ts * 8 + cand];
            const float4* xr = (const float4*)(x + (size_t)(tok0 + ts) * HDIM);
            const float4* wr = (const float4*)(w + (size_t)ce * HDIM);
            double q0 = 0.0, q1 = 0.0, q2 = 0.0, q3 = 0.0;
            for (int i2 = 0; i2 < 12; ++i2) {
                int fi = lane + i2 * 64;
                if (fi < HDIM / 4) {
                    float4 xv = xr[fi];
                    float4 wv4 = wr[fi];
                    q0 = fma((double)xv.x, (double)wv4.x, q0);
                    q1 = fma((double)xv.y, (double)wv4.y, q1);
                    q2 = fma((double)xv.z, (double)wv4.z, q2);
                    q3 = fma((double)xv.w, (double)wv4.w, q3);
                }
            }
            double accd = (q0 + q2) + (q1 + q3);
#pragma unroll
            for (int off = 32; off > 0; off >>= 1)
                accd += __shfl_xor(accd, off);
            if (lane == 0) cvd[cand] = accd + (double)bias[ce];
        }
        __syncthreads();
        if (tid < 8) {                        // fp64 rank among 8 candidates
            double mv = cvd[tid]; int mi2 = cie[ts * 8 + tid];
            int rk = 0;
#pragma unroll
            for (int j2 = 0; j2 < 8; ++j2) {
                double oj = cvd[j2];
                rk += (oj > mv) || (oj == mv && cie[ts * 8 + j2] < mi2);
            }
            if (rk < 4) { svd[ts * 4 + rk] = mv; sid[ts * 4 + rk] = mi2; }
        }
        __syncthreads();
    }

    // -------- softmax + outputs ---------------------------------------------
    float* srow = (float*)smem;              // [32][128], overlays dead logits
    float4 z4 = make_float4(0.f, 0.f, 0.f, 0.f);
#pragma unroll
    for (int i = 0; i < 4; ++i)
        ((float4*)srow)[tid + i * NT] = z4;
    __syncthreads();

    if (tid < TM) {
        double m  = svd[tid * 4];
        double e0 = exp(svd[tid * 4 + 0] - m), e1 = exp(svd[tid * 4 + 1] - m);
        double e2 = exp(svd[tid * 4 + 2] - m), e3 = exp(svd[tid * 4 + 3] - m);
        double inv = 1.0 / ((e0 + e1) + (e2 + e3));
        float* oidx = out + (size_t)T_TOK * EEXP + (size_t)(tok0 + tid) * KTOP;
        int i0 = sid[tid * 4 + 0], i1 = sid[tid * 4 + 1];
        int i2 = sid[tid * 4 + 2], i3 = sid[tid * 4 + 3];
        oidx[0] = (float)i0; oidx[1] = (float)i1;
        oidx[2] = (float)i2; oidx[3] = (float)i3;
        srow[tid * EEXP + i0] = (float)(e0 * inv);
        srow[tid * EEXP + i1] = (float)(e1 * inv);
        srow[tid * EEXP + i2] = (float)(e2 * inv);
        srow[tid * EEXP + i3] = (float)(e3 * inv);
    }
    __syncthreads();

    float4* orow = (float4*)(out + (size_t)tok0 * EEXP);
#pragma unroll
    for (int i = 0; i < 4; ++i)
        orow[tid + i * NT] = ((float4*)srow)[tid + i * NT];
}

extern "C" void kernel_launch(void* const* d_in, const int* in_sizes, int n_in,
                              void* d_out, int out_size, void* d_ws, size_t ws_size,
                              hipStream_t stream) {
    const float* x    = (const float*)d_in[0];
    const float* w    = (const float*)d_in[1];
    const float* bias = (const float*)d_in[2];
    float* out        = (float*)d_out;
    char*  wp         = (char*)d_ws;   // needs 1440 KiB (8*45*2*2 tiles * 1KB)

    hipLaunchKernelGGL(w_split, dim3(180), dim3(256), 0, stream, w, wp);
    hipLaunchKernelGGL(router_fused, dim3(T_TOK / TM), dim3(NT), 0, stream,
                       x, wp, w, bias, out);
}

// Round 12
// 80.215 us; speedup vs baseline: 1.7244x; 1.0608x over previous
//
#include <hip/hip_runtime.h>
#include <math.h>

// GptOssRouter: T=16384, H=2880, E=128, K=4.
// K0: pre-split w (fp32 -> bf16 h/l, trunc-exact) into d_ws, tiled as MFMA
//     B-fragments: tile(F,c,ks,p)[lane] = 8 bf16 of
//     w[F*16+(lane&15)][c*64+ks*32+(lane>>4)*8 ...].
// K1 (fused): 32 tokens x 128 experts per block, grid=512 (2 blocks/CU).
//     DEPTH-3 software pipeline (unroll-3, static buffer roles): x loads 3
//     chunks ahead into 3 named reg buffers, w frags 2-3 phases ahead, 3 LDS
//     x-buffers. 3-pass split-bf16 MFMA: xh*wh + xh*wl + xl*wh (err ~1e-5).
//     Fused stripe-top8 + certified-gap test (TAU=2.5e-4): fast fp32 softmax;
//     rare fp64 re-accumulation slow path (order == float64 numpy reference).

#define T_TOK 16384
#define HDIM  2880
#define EEXP  128
#define KTOP  4

#define TM   32
#define NT   256
#define KC   64
#define NCH  (HDIM / KC)     // 45 = 15 * 3
#define XBUF 8192            // 32 rows * 256 B
#define TAU  2.5e-4f

typedef __attribute__((ext_vector_type(8))) short bf16x8;
typedef __attribute__((ext_vector_type(4))) float f32x4;

#define MFMA(a, b, c) __builtin_amdgcn_mfma_f32_16x16x32_bf16((a), (b), (c), 0, 0, 0)

// ---------------- K0: w pre-split into fragment-tiled bf16 h/l -------------
__global__ __launch_bounds__(256) void w_split(
    const float* __restrict__ w, char* __restrict__ wp)
{
    const int gid  = blockIdx.x * 256 + threadIdx.x;   // 46080 total
    const int lane = gid & 63;
    const int q    = gid >> 6;        // 0..719
    const int ks   = q & 1;
    const int q2   = q >> 1;          // 0..359
    const int c    = q2 % NCH;
    const int F    = q2 / NCH;        // 0..7
    const int e    = F * 16 + (lane & 15);
    const int k0   = c * 64 + ks * 32 + (lane >> 4) * 8;

    const float* src = w + (size_t)e * HDIM + k0;
    float4 v0 = *(const float4*)(src);
    float4 v1 = *(const float4*)(src + 4);
    float vv[8] = {v0.x, v0.y, v0.z, v0.w, v1.x, v1.y, v1.z, v1.w};
    union { unsigned short s[8]; uint4 u; } H, L;
#pragma unroll
    for (int j = 0; j < 8; ++j) {
        unsigned u = __float_as_uint(vv[j]);
        H.s[j] = (unsigned short)(u >> 16);
        float rr = vv[j] - __uint_as_float(u & 0xffff0000u);
        L.s[j] = (unsigned short)(__float_as_uint(rr) >> 16);
    }
    const int tile = ((F * NCH + c) * 2 + ks) * 2;     // p=0 (h); l at +1
    *(uint4*)(wp + (size_t)tile * 1024 + lane * 16)       = H.u;
    *(uint4*)(wp + (size_t)(tile + 1) * 1024 + lane * 16) = L.u;
}

// x split: v = h + l (h = trunc_bf16(v), l = trunc_bf16(v - h), both exact);
// h 8B at swizzled slot, l at +128 within the 256B row.
static __device__ __forceinline__ void split_write256(char* base, int off, float4 v) {
    union { float4 v4; unsigned u[4]; } uv; uv.v4 = v;
    unsigned h01 = __builtin_amdgcn_perm(uv.u[1], uv.u[0], 0x07060302u);
    unsigned h23 = __builtin_amdgcn_perm(uv.u[3], uv.u[2], 0x07060302u);
    float r0 = v.x - __uint_as_float(uv.u[0] & 0xffff0000u);
    float r1 = v.y - __uint_as_float(uv.u[1] & 0xffff0000u);
    float r2 = v.z - __uint_as_float(uv.u[2] & 0xffff0000u);
    float r3 = v.w - __uint_as_float(uv.u[3] & 0xffff0000u);
    unsigned l01 = __builtin_amdgcn_perm(__float_as_uint(r1), __float_as_uint(r0), 0x07060302u);
    unsigned l23 = __builtin_amdgcn_perm(__float_as_uint(r3), __float_as_uint(r2), 0x07060302u);
    uint2 hw; hw.x = h01; hw.y = h23;
    uint2 lw; lw.x = l01; lw.y = l23;
    *(uint2*)(base + off)       = hw;
    *(uint2*)(base + off + 128) = lw;
}

// ---------------- K1: fused GEMM + selection --------------------------------
__global__ __launch_bounds__(NT, 2) void router_fused(
    const float* __restrict__ x, const char* __restrict__ wp,
    const float* __restrict__ w, const float* __restrict__ bias,
    float* __restrict__ out)
{
    __shared__ char smem[3 * XBUF];     // 24576 B
    const int tid  = threadIdx.x;
    const int tok0 = blockIdx.x * TM;
    const int lane = tid & 63;
    const int wv   = tid >> 6;          // expert 32-group 0..3
    const int r    = lane & 15;
    const int g    = lane >> 4;

    char* xb0 = smem;
    char* xb1 = smem + XBUF;
    char* xb2 = smem + 2 * XBUF;

    // x staging map: 512 float4 / 256 thr = 2 per thread
    int xoff[2];
    const float* xptr[2];
#pragma unroll
    for (int i = 0; i < 2; ++i) {
        int f = tid + i * NT;
        int row = f >> 4, c4 = f & 15;
        xoff[i] = row * 256 + ((((c4 >> 1) ^ (row & 7)) << 4) | ((c4 & 1) << 3));
        xptr[i] = x + (size_t)(tok0 + row) * HDIM + c4 * 4;
    }

    // a-frag read offsets: [tokfrag][ks]
    int aoff[2][2];
#pragma unroll
    for (int tf = 0; tf < 2; ++tf) {
        int row = tf * 16 + r;
#pragma unroll
        for (int ks = 0; ks < 2; ++ks)
            aoff[tf][ks] = row * 256 + (((ks * 4 + g) ^ (row & 7)) << 4);
    }

    f32x4 a00 = {0.f, 0.f, 0.f, 0.f}, a01 = a00, a10 = a00, a11 = a00;

#define LOADX(pf, cc) do {                                            \
        pf[0] = *(const float4*)(xptr[0] + (cc) * KC);                \
        pf[1] = *(const float4*)(xptr[1] + (cc) * KC); } while (0)

#define WRITEX(pf, bb) do {                                           \
        split_write256((bb), xoff[0], pf[0]);                         \
        split_write256((bb), xoff[1], pf[1]); } while (0)

    // w frag tiles: idx = F2*4 + ks*2 + p
#define LOADW(W, cc) do {                                             \
        _Pragma("unroll")                                             \
        for (int F2 = 0; F2 < 2; ++F2)                                \
        _Pragma("unroll")                                             \
        for (int ks_ = 0; ks_ < 2; ++ks_)                             \
        _Pragma("unroll")                                             \
        for (int p_ = 0; p_ < 2; ++p_)                                \
            W[F2*4 + ks_*2 + p_] = *(const bf16x8*)(wp +              \
                (size_t)((((wv*2 + F2) * NCH + (cc)) * 2 + ks_) * 2 + p_) * 1024 \
                + lane * 16); } while (0)

#define MFMA_CHUNK(cb, W) do {                                        \
        _Pragma("unroll")                                             \
        for (int ks_ = 0; ks_ < 2; ++ks_) {                           \
            bf16x8 ah0 = *(const bf16x8*)((cb) + aoff[0][ks_]);       \
            bf16x8 al0 = *(const bf16x8*)((cb) + aoff[0][ks_] + 128); \
            bf16x8 ah1 = *(const bf16x8*)((cb) + aoff[1][ks_]);       \
            bf16x8 al1 = *(const bf16x8*)((cb) + aoff[1][ks_] + 128); \
            bf16x8 bh0 = W[ks_*2],     bl0 = W[ks_*2 + 1];            \
            bf16x8 bh1 = W[4 + ks_*2], bl1 = W[4 + ks_*2 + 1];        \
            a00 = MFMA(ah0, bh0, a00); a01 = MFMA(ah0, bh1, a01);     \
            a10 = MFMA(ah1, bh0, a10); a11 = MFMA(ah1, bh1, a11);     \
            a00 = MFMA(ah0, bl0, a00); a01 = MFMA(ah0, bl1, a01);     \
            a10 = MFMA(ah1, bl0, a10); a11 = MFMA(ah1, bl1, a11);     \
            a00 = MFMA(al0, bh0, a00); a01 = MFMA(al0, bh1, a01);     \
            a10 = MFMA(al1, bh0, a10); a11 = MFMA(al1, bh1, a11);     \
        } } while (0)

    float4 pfA[2], pfB[2], pfC[2];
    bf16x8 wA[8], wB[8], wC[8];

    // prologue: chunks 0..2 in regs, chunk 0 -> xb0; w chunks 0,1 in regs
    LOADX(pfA, 0); LOADX(pfB, 1); LOADX(pfC, 2);
    LOADW(wA, 0); LOADW(wB, 1);
    WRITEX(pfA, xb0);
    __syncthreads();

    for (int c = 0; c < NCH; c += 3) {
        // ---- phase 0: chunk c on xb0 / wA --------------------------------
        if (c + 3 < NCH) LOADX(pfA, c + 3);
        LOADW(wC, c + 2);
        MFMA_CHUNK(xb0, wA);
        WRITEX(pfB, xb1);                 // chunk c+1 (loaded 3 phases ago)
        __syncthreads();
        // ---- phase 1: chunk c+1 on xb1 / wB ------------------------------
        if (c + 3 < NCH) LOADW(wA, c + 3);
        if (c + 4 < NCH) LOADX(pfB, c + 4);
        MFMA_CHUNK(xb1, wB);
        WRITEX(pfC, xb2);                 // chunk c+2
        __syncthreads();
        // ---- phase 2: chunk c+2 on xb2 / wC ------------------------------
        if (c + 4 < NCH) LOADW(wB, c + 4);
        if (c + 5 < NCH) LOADX(pfC, c + 5);
        MFMA_CHUNK(xb2, wC);
        if (c + 3 < NCH) WRITEX(pfA, xb0); // chunk c+3
        __syncthreads();
    }

    // -------- logits(+bias) -> LDS [32][130] --------------------------------
    float* logitsL = (float*)smem;
    const float bv0 = bias[wv * 32 + r];
    const float bv1 = bias[wv * 32 + 16 + r];
#pragma unroll
    for (int q = 0; q < 4; ++q) {
        int m0 = g * 4 + q, m1 = m0 + 16;
        int e0 = wv * 32 + r, e1 = e0 + 16;
        logitsL[m0 * 130 + e0] = a00[q] + bv0;
        logitsL[m0 * 130 + e1] = a01[q] + bv1;
        logitsL[m1 * 130 + e0] = a10[q] + bv0;
        logitsL[m1 * 130 + e1] = a11[q] + bv1;
    }
    float*  cvf = (float*) (smem + 16640);   // [32][8]
    int*    cie = (int*)   (smem + 17664);   // [32][8]
    int*    flg = (int*)   (smem + 18688);   // [32]
    double* svd = (double*)(smem + 18816);   // [32][4]
    int*    sid = (int*)   (smem + 19840);   // [32][4]
    double* cvd = (double*)(smem + 20352);   // [8]
    __syncthreads();

    // -------- stripe top-8: thread (t, s) scans experts [s*16, s*16+16) -----
    {
        const int t = tid >> 3, s = tid & 7;
        float v[8]; int id[8];
#pragma unroll
        for (int k = 0; k < 8; ++k) { v[k] = -3.4e38f; id[k] = 0x7fffffff; }
        for (int jj = 0; jj < 16; ++jj) {
            float lv = logitsL[t * 130 + s * 16 + jj];
            int   e  = s * 16 + jj;
            bool gt[8];
#pragma unroll
            for (int k = 0; k < 8; ++k)
                gt[k] = (lv > v[k]) || (lv == v[k] && e < id[k]);
#pragma unroll
            for (int k = 7; k >= 1; --k)
                if (gt[k - 1]) { v[k] = v[k - 1]; id[k] = id[k - 1]; }
#pragma unroll
            for (int k = 0; k < 8; ++k) {
                bool put = gt[k] && (k == 0 || !gt[k - 1]);
                if (put) { v[k] = lv; id[k] = e; }
            }
        }
#pragma unroll
        for (int rd = 0; rd < 8; ++rd) {
            float hv = v[0]; int hi = id[0];
#pragma unroll
            for (int off = 1; off < 8; off <<= 1) {
                float ov = __shfl_xor(hv, off);
                int   oi = __shfl_xor(hi, off);
                if (ov > hv || (ov == hv && oi < hi)) { hv = ov; hi = oi; }
            }
            if (s == 0) { cvf[t * 8 + rd] = hv; cie[t * 8 + rd] = hi; }
            bool mine = (v[0] == hv) && (id[0] == hi);
            if (mine) {
#pragma unroll
                for (int k = 0; k < 7; ++k) { v[k] = v[k + 1]; id[k] = id[k + 1]; }
                v[7] = -3.4e38f; id[7] = 0x7fffffff;
            }
        }
    }
    __syncthreads();

    // -------- certified-gap test + fast-path fill ---------------------------
    if (tid < TM) {
        float gmin = 3.4e38f;
#pragma unroll
        for (int k = 0; k < 4; ++k)
            gmin = fminf(gmin, cvf[tid * 8 + k] - cvf[tid * 8 + k + 1]);
        flg[tid] = (gmin < TAU);
    }
    if (tid < 128) {
        int t2 = tid >> 2, k = tid & 3;
        svd[t2 * 4 + k] = (double)cvf[t2 * 8 + k];
        sid[t2 * 4 + k] = cie[t2 * 8 + k];
    }
    __syncthreads();

    // -------- rare slow path: fp64 rescore (2 candidates per wave) ----------
    for (int ts = 0; ts < TM; ++ts) {
        if (!flg[ts]) continue;              // uniform across block
#pragma unroll
        for (int h2 = 0; h2 < 2; ++h2) {
            const int cand = wv * 2 + h2;
            const int ce = cie[ts * 8 + cand];
            const float4* xr = (const float4*)(x + (size_t)(tok0 + ts) * HDIM);
            const float4* wr = (const float4*)(w + (size_t)ce * HDIM);
            double q0 = 0.0, q1 = 0.0, q2 = 0.0, q3 = 0.0;
            for (int i2 = 0; i2 < 12; ++i2) {
                int fi = lane + i2 * 64;
                if (fi < HDIM / 4) {
                    float4 xv = xr[fi];
                    float4 wv4 = wr[fi];
                    q0 = fma((double)xv.x, (double)wv4.x, q0);
                    q1 = fma((double)xv.y, (double)wv4.y, q1);
                    q2 = fma((double)xv.z, (double)wv4.z, q2);
                    q3 = fma((double)xv.w, (double)wv4.w, q3);
                }
            }
            double accd = (q0 + q2) + (q1 + q3);
#pragma unroll
            for (int off = 32; off > 0; off >>= 1)
                accd += __shfl_xor(accd, off);
            if (lane == 0) cvd[cand] = accd + (double)bias[ce];
        }
        __syncthreads();
        if (tid < 8) {                        // fp64 rank among 8 candidates
            double mv = cvd[tid]; int mi2 = cie[ts * 8 + tid];
            int rk = 0;
#pragma unroll
            for (int j2 = 0; j2 < 8; ++j2) {
                double oj = cvd[j2];
                rk += (oj > mv) || (oj == mv && cie[ts * 8 + j2] < mi2);
            }
            if (rk < 4) { svd[ts * 4 + rk] = mv; sid[ts * 4 + rk] = mi2; }
        }
        __syncthreads();
    }

    // -------- softmax + outputs ---------------------------------------------
    float* srow = (float*)smem;              // [32][128], overlays dead logits
    float4 z4 = make_float4(0.f, 0.f, 0.f, 0.f);
#pragma unroll
    for (int i = 0; i < 4; ++i)
        ((float4*)srow)[tid + i * NT] = z4;
    __syncthreads();

    if (tid < TM) {
        double m  = svd[tid * 4];
        double e0 = exp(svd[tid * 4 + 0] - m), e1 = exp(svd[tid * 4 + 1] - m);
        double e2 = exp(svd[tid * 4 + 2] - m), e3 = exp(svd[tid * 4 + 3] - m);
        double inv = 1.0 / ((e0 + e1) + (e2 + e3));
        float* oidx = out + (size_t)T_TOK * EEXP + (size_t)(tok0 + tid) * KTOP;
        int i0 = sid[tid * 4 + 0], i1 = sid[tid * 4 + 1];
        int i2 = sid[tid * 4 + 2], i3 = sid[tid * 4 + 3];
        oidx[0] = (float)i0; oidx[1] = (float)i1;
        oidx[2] = (float)i2; oidx[3] = (float)i3;
        srow[tid * EEXP + i0] = (float)(e0 * inv);
        srow[tid * EEXP + i1] = (float)(e1 * inv);
        srow[tid * EEXP + i2] = (float)(e2 * inv);
        srow[tid * EEXP + i3] = (float)(e3 * inv);
    }
    __syncthreads();

    float4* orow = (float4*)(out + (size_t)tok0 * EEXP);
#pragma unroll
    for (int i = 0; i < 4; ++i)
        orow[tid + i * NT] = ((float4*)srow)[tid + i * NT];
}

extern "C" void kernel_launch(void* const* d_in, const int* in_sizes, int n_in,
                              void* d_out, int out_size, void* d_ws, size_t ws_size,
                              hipStream_t stream) {
    const float* x    = (const float*)d_in[0];
    const float* w    = (const float*)d_in[1];
    const float* bias = (const float*)d_in[2];
    float* out        = (float*)d_out;
    char*  wp         = (char*)d_ws;   // needs 1440 KiB (8*45*2*2 tiles * 1KB)

    hipLaunchKernelGGL(w_split, dim3(180), dim3(256), 0, stream, w, wp);
    hipLaunchKernelGGL(router_fused, dim3(T_TOK / TM), dim3(NT), 0, stream,
                       x, wp, w, bias, out);
}